// Round 7
// baseline (42.950 us; speedup 1.0000x reference)
//
#include <hip/hip_runtime.h>

#define BATCH 999
#define HID 1024
#define SEQ 160

#define BB 64                         // batches per block (4 waves x 16)
#define WB 16                         // batches per wave
#define NBB 16                        // 16 * 64 = 1024 >= 999
#define KS 2                          // k-split
#define KPER (HID / KS)               // 512 k per block
#define HS 16                         // h-split
#define HPER (HID / HS)               // 64 h per block
#define NTILE (KS * HS)               // 32 hk-tiles per b-group

// Cross-block staging (device-coherent access only; zero-init not required:
// every slot is written each launch before it is read).
__device__ float gpart[NTILE][NBB][BB];     // 131 KB
__device__ unsigned gcnt[NBB];              // wraps mod 32 each launch: no reset

__global__ __launch_bounds__(256, 2)
void dots_kernel(const float* __restrict__ Cg, const float* __restrict__ Rg,
                 const float* __restrict__ Mg, float* __restrict__ out)
{
    __shared__ float sC[HPER][BB];    // 16 KB, C transposed: sC[h][b]
    __shared__ float sRed[4][BB];     // 1 KB, tail reduction
    __shared__ int sdone;

    const int tid  = threadIdx.x;
    const int lane = tid & 63;
    const int w    = tid >> 6;        // wave id 0..3 -> owns 16 batches

    // XCD-aware bijective decode: per-XCD working set ~3.5 MB < 4 MB L2
    const int L    = blockIdx.x;      // 0..511
    const int xcd  = L & 7;
    const int slot = L >> 3;          // 0..63
    const int tile = xcd * 4 + (slot & 3);   // 0..31
    const int by   = slot >> 2;       // 0..15
    const int kx   = tile >> 4;       // 0..1
    const int hz   = tile & 15;       // 0..15
    const int b0   = by * BB;
    const int k0   = kx * KPER;
    const int h0   = hz * HPER;

    // Per-wave / per-block h-phase: de-correlates the vmcnt/lgkmcnt stall
    // points of the waves sharing a SIMD (h-sum is order-independent).
    const int phase = ((w + (L & 3) + ((L >> 8) & 3)) & 3) << 4;  // 0/16/32/48

    // ---- stage C slice once: sC[h][b] = C[b0+b][last, h0+h] ----
    {
        const int b  = tid & 63;
        const int hq = tid >> 6;      // 0..3, 16 h-values each
        const int gb = b0 + b;
        float4 v[4];
        #pragma unroll
        for (int q = 0; q < 4; ++q) v[q] = make_float4(0.f, 0.f, 0.f, 0.f);
        if (gb < BATCH) {
            const float* cp = Cg + ((size_t)gb * SEQ + (SEQ - 1)) * HID + h0 + hq * 16;
            #pragma unroll
            for (int q = 0; q < 4; ++q) v[q] = *(const float4*)(cp + 4 * q);
        }
        // bank = b&31 -> 2-way wave64 aliasing = free
        #pragma unroll
        for (int q = 0; q < 4; ++q) {
            sC[hq * 16 + q * 4 + 0][b] = v[q].x;
            sC[hq * 16 + q * 4 + 1][b] = v[q].y;
            sC[hq * 16 + q * 4 + 2][b] = v[q].z;
            sC[hq * 16 + q * 4 + 3][b] = v[q].w;
        }
    }
    __syncthreads();

    float4 acc[WB][2]; // 16 batches x 8 k-floats
    #pragma unroll
    for (int i = 0; i < WB; ++i) {
        acc[i][0] = make_float4(0.f, 0.f, 0.f, 0.f);
        acc[i][1] = make_float4(0.f, 0.f, 0.f, 0.f);
    }

    // M rows straight from global (L1/L2-resident, coalesced 16B/lane),
    // two-row register prefetch, NO barriers, NO LDS for M.
    // Row order is rotated by `phase` (mod 64) per wave/block.
    const float* mbase = Mg + (size_t)h0 * HID + k0 + (lane << 2);

    auto rowof = [&](int hh) { return (hh + phase) & 63; };

    auto fmah = [&](int row, float4 ma, float4 mb) {
        const float* crow = &sC[row][w << 4];
        const float4 c0 = *(const float4*)(crow);       // wave-uniform broadcasts
        const float4 c1 = *(const float4*)(crow + 4);
        const float4 c2 = *(const float4*)(crow + 8);
        const float4 c3 = *(const float4*)(crow + 12);
        const float cs[WB] = {c0.x, c0.y, c0.z, c0.w, c1.x, c1.y, c1.z, c1.w,
                              c2.x, c2.y, c2.z, c2.w, c3.x, c3.y, c3.z, c3.w};
        #pragma unroll
        for (int i = 0; i < WB; ++i) {
            acc[i][0].x += cs[i] * ma.x; acc[i][0].y += cs[i] * ma.y;
            acc[i][0].z += cs[i] * ma.z; acc[i][0].w += cs[i] * ma.w;
            acc[i][1].x += cs[i] * mb.x; acc[i][1].y += cs[i] * mb.y;
            acc[i][1].z += cs[i] * mb.z; acc[i][1].w += cs[i] * mb.w;
        }
    };

    const float* p0 = mbase + ((size_t)rowof(0) << 10);
    const float* p1 = mbase + ((size_t)rowof(1) << 10);
    float4 m0a = *(const float4*)(p0);
    float4 m0b = *(const float4*)(p0 + 256);
    float4 m1a = *(const float4*)(p1);
    float4 m1b = *(const float4*)(p1 + 256);

    for (int hh = 0; hh < HPER - 2; hh += 2) {
        const float* q0 = mbase + ((size_t)rowof(hh + 2) << 10);
        const float* q1 = mbase + ((size_t)rowof(hh + 3) << 10);
        float4 n0a = *(const float4*)(q0);
        float4 n0b = *(const float4*)(q0 + 256);
        float4 n1a = *(const float4*)(q1);
        float4 n1b = *(const float4*)(q1 + 256);
        fmah(rowof(hh), m0a, m0b);
        fmah(rowof(hh + 1), m1a, m1b);
        m0a = n0a; m0b = n0b; m1a = n1a; m1b = n1b;
    }
    fmah(rowof(HPER - 2), m0a, m0b);
    fmah(rowof(HPER - 1), m1a, m1b);

    // ---- epilogue: dot with R row-slice, butterfly, coherent partial store ----
    #pragma unroll
    for (int i = 0; i < WB; ++i) {
        const int gb = b0 + w * WB + i;
        float p = 0.f;
        if (gb < BATCH) {
            const float* rp = Rg + ((size_t)gb * SEQ + (SEQ - 1)) * HID + k0 + (lane << 2);
            const float4 r0 = *(const float4*)(rp);
            const float4 r1 = *(const float4*)(rp + 256);
            p = acc[i][0].x * r0.x + acc[i][0].y * r0.y + acc[i][0].z * r0.z + acc[i][0].w * r0.w
              + acc[i][1].x * r1.x + acc[i][1].y * r1.y + acc[i][1].z * r1.z + acc[i][1].w * r1.w;
        }
        #pragma unroll
        for (int m = 1; m < 64; m <<= 1) p += __shfl_xor(p, m, 64);
        if (lane == 0)
            __hip_atomic_store(&gpart[tile][by][w * WB + i], p,
                               __ATOMIC_RELAXED, __HIP_MEMORY_SCOPE_AGENT);
    }

    // ---- completion protocol: drain stores to coherence point -> counter ----
    asm volatile("s_waitcnt vmcnt(0)" ::: "memory");
    __syncthreads();
    if (tid == 0) {
        unsigned old = __hip_atomic_fetch_add(&gcnt[by], 1u,
                                              __ATOMIC_RELAXED, __HIP_MEMORY_SCOPE_AGENT);
        sdone = ((old & (NTILE - 1)) == (NTILE - 1));
    }
    __syncthreads();

    // ---- fused tail: last-arrival block reduces 32 partials + sigmoid ----
    if (sdone) {
        const int b = tid & 63;
        const int q = tid >> 6;       // 0..3 -> 8 tiles each
        float s = 0.f;
        #pragma unroll
        for (int t = 0; t < 8; ++t)
            s += __hip_atomic_load(&gpart[q * 8 + t][by][b],
                                   __ATOMIC_RELAXED, __HIP_MEMORY_SCOPE_AGENT);
        sRed[q][b] = s;
        __syncthreads();
        if (tid < BB) {
            const int gb = b0 + tid;
            if (gb < BATCH) {
                float d = sRed[0][tid] + sRed[1][tid] + sRed[2][tid] + sRed[3][tid];
                out[gb] = 1.f / (1.f + __expf(-d));
            }
        }
    }
}

extern "C" void kernel_launch(void* const* d_in, const int* in_sizes, int n_in,
                              void* d_out, int out_size, void* d_ws, size_t ws_size,
                              hipStream_t stream) {
    const float* ctx = (const float*)d_in[0];
    const float* rsp = (const float*)d_in[1];
    const float* M   = (const float*)d_in[2];
    float* out = (float*)d_out;
    (void)d_ws; (void)ws_size;

    dim3 grid(NBB * NTILE);   // 512 blocks, 1-D XCD-aware decode, 2/CU
    dots_kernel<<<grid, 256, 0, stream>>>(ctx, rsp, M, out);
}